// Round 1
// baseline (1623.225 us; speedup 1.0000x reference)
//
#include <hip/hip_runtime.h>

#define NTOK   32768
#define DDIM   512
#define KCODES 8192
#define DK     (DDIM * KCODES)      // 4194304
#define DECAYF 0.8f
#define EPSF   1e-5f

using short8 = __attribute__((ext_vector_type(8))) short;
using f32x4  = __attribute__((ext_vector_type(4))) float;

// ---------------- ws layout (float offsets) ----------------
#define WS_ESUMT   0                          // [K][D] fp32 accum (zeroed)
#define WS_ONEHOT  DK                         // [K] (zeroed)
#define WS_ENORM   (DK + 8192)                // [K] (zeroed, atomic accum)
#define WS_SCAL    (DK + 16384)               // [16]: 0=loss, 1=nsum (zeroed)
#define WS_PART    (DK + 16400)               // NTOK u64, memset 0xFF (= u64 max)
#define WS_EMBEDT  (WS_PART + 2 * NTOK)       // [K][D] fp32 transposed codebook
#define WS_EHI     (WS_EMBEDT + DK)           // [K][D] bf16 hi (DK ushorts)
#define WS_ELO     (WS_EHI + DK / 2)          // [K][D] bf16 lo
#define WS_ZERO_BYTES ((size_t)(DK + 16400) * 4)

__device__ __forceinline__ unsigned short bf16rne(float f) {
  unsigned u = __float_as_uint(f);
  unsigned r = u + 0x7FFFu + ((u >> 16) & 1u);
  return (unsigned short)(r >> 16);
}

__device__ __forceinline__ void gload_lds16(const unsigned short* g, unsigned short* l) {
  __builtin_amdgcn_global_load_lds(
      (const __attribute__((address_space(1))) unsigned int*)g,
      (__attribute__((address_space(3))) unsigned int*)l, 16, 0, 0);
}

// ============ K1: split x into bf16 hi/lo ============
__global__ __launch_bounds__(256) void split_x_kernel(
    const float* __restrict__ x, unsigned short* __restrict__ hi,
    unsigned short* __restrict__ lo) {
  const size_t i = ((size_t)blockIdx.x * 256 + threadIdx.x) * 8;
  const float4 v0 = *(const float4*)&x[i];
  const float4 v1 = *(const float4*)&x[i + 4];
  const float v[8] = {v0.x, v0.y, v0.z, v0.w, v1.x, v1.y, v1.z, v1.w};
  unsigned short h[8], l[8];
#pragma unroll
  for (int j = 0; j < 8; ++j) {
    h[j] = bf16rne(v[j]);
    l[j] = bf16rne(v[j] - __uint_as_float((unsigned)h[j] << 16));
  }
  uint4 H, L;
  H.x = h[0] | ((unsigned)h[1] << 16); H.y = h[2] | ((unsigned)h[3] << 16);
  H.z = h[4] | ((unsigned)h[5] << 16); H.w = h[6] | ((unsigned)h[7] << 16);
  L.x = l[0] | ((unsigned)l[1] << 16); L.y = l[2] | ((unsigned)l[3] << 16);
  L.z = l[4] | ((unsigned)l[5] << 16); L.w = l[6] | ((unsigned)l[7] << 16);
  *(uint4*)&hi[i] = H;
  *(uint4*)&lo[i] = L;
}

// ============ K2: transpose embed [D][K]->[K][D] fp32 + bf16 hi/lo + e_norm ============
__global__ __launch_bounds__(256) void transpose_split_kernel(
    const float* __restrict__ embed, float* __restrict__ embedT,
    unsigned short* __restrict__ ehi, unsigned short* __restrict__ elo,
    float* __restrict__ e_norm) {
  __shared__ float tile[32][33];
  __shared__ float part[8][32];
  const int k0 = blockIdx.x * 32;
  const int d0 = blockIdx.y * 32;
  const int tx = threadIdx.x;   // 0..31
  const int ty = threadIdx.y;   // 0..7
  float sq = 0.f;
#pragma unroll
  for (int j = 0; j < 4; ++j) {
    const int dl = ty + j * 8;
    const float v = embed[(size_t)(d0 + dl) * KCODES + k0 + tx];
    tile[dl][tx] = v;
    sq += v * v;
  }
  part[ty][tx] = sq;
  __syncthreads();
  if (ty == 0) {
    float s = 0.f;
#pragma unroll
    for (int j = 0; j < 8; ++j) s += part[j][tx];
    atomicAdd(&e_norm[k0 + tx], s);
  }
#pragma unroll
  for (int j = 0; j < 4; ++j) {
    const int kl = ty + j * 8;
    const size_t idx = (size_t)(k0 + kl) * DDIM + d0 + tx;
    const float v = tile[tx][kl];
    embedT[idx] = v;
    const unsigned short h = bf16rne(v);
    ehi[idx] = h;
    elo[idx] = bf16rne(v - __uint_as_float((unsigned)h << 16));
  }
}

// ============ K3: fused 3-product bf16-split MFMA dist GEMM + argmin ============
// 8-phase-style pipeline (T3+T4+T5): tile 128(tok)x256(code), BK=32, 8 waves,
// 3-deep LDS buffers (144 KB), counted vmcnt(6) gate (never drains in loop),
// prefetch of tile t+2 interleaved across the 4 compute phases.
// LDS XOR swizzle (unchanged from prev version): stored group c holds global
// group c ^ ((row>>1)&3); reads apply same XOR -> 0 bank conflicts.
#define MFMA(d, a, b) d = __builtin_amdgcn_mfma_f32_16x16x32_bf16(a, b, d, 0, 0, 0)

__global__ __launch_bounds__(512, 2) void argmin_mfma_kernel(
    const unsigned short* __restrict__ xhi, const unsigned short* __restrict__ xlo,
    const unsigned short* __restrict__ ehi, const unsigned short* __restrict__ elo,
    const float* __restrict__ e_norm, unsigned long long* __restrict__ partials) {
  __shared__ unsigned short Ah[3][128 * 32];   // 3 x 8 KB
  __shared__ unsigned short Al[3][128 * 32];   // 3 x 8 KB
  __shared__ unsigned short Bh[3][256 * 32];   // 3 x 16 KB
  __shared__ unsigned short Bl[3][256 * 32];   // 3 x 16 KB  => 144 KB total

  const int tid = threadIdx.x;
  const int wid = tid >> 6;          // 0..7
  const int lid = tid & 63;
  const int kbase   = blockIdx.x * 256;
  const int tokbase = blockIdx.y * 128;

  const int wrow = wid >> 2;         // 0..1  (token 64-row block)
  const int wcol = wid & 3;          // 0..3  (code 64-col block)
  const int m16 = lid & 15, kq = lid >> 4;

  // staging lane mapping: row-within-16-chunk + swizzled source colgroup
  const int srow = lid >> 2;                                  // 0..15
  const int gcol = ((lid & 3) ^ ((srow >> 1) & 3)) * 8;       // swizzled source
  // ds_read swizzle for fragment loads
  const int fsw = (kq ^ ((m16 >> 1) & 3)) * 8;

  f32x4 acc[4][4];
#pragma unroll
  for (int i = 0; i < 4; ++i)
#pragma unroll
    for (int j = 0; j < 4; ++j) acc[i][j] = (f32x4)0.f;

  // per-lane global sources (ushort units); tile t adds t*32
  const unsigned short* Ahg  = xhi + (size_t)(tokbase + wid * 16 + srow) * DDIM + gcol;
  const unsigned short* Alg  = xlo + (size_t)(tokbase + wid * 16 + srow) * DDIM + gcol;
  const unsigned short* Bhg0 = ehi + (size_t)(kbase + wid * 16 + srow) * DDIM + gcol;
  const unsigned short* Bhg1 = ehi + (size_t)(kbase + (wid + 8) * 16 + srow) * DDIM + gcol;
  const unsigned short* Blg0 = elo + (size_t)(kbase + wid * 16 + srow) * DDIM + gcol;
  const unsigned short* Blg1 = elo + (size_t)(kbase + (wid + 8) * 16 + srow) * DDIM + gcol;

  // fragment LDS offsets (ushort units); frag i/j adds i*512 / j*512
  const int aoff = (wrow * 64 + m16) * 32 + fsw;
  const int boff = (wcol * 64 + m16) * 32 + fsw;

  // -------- prologue: tile 0 -> buf 0, tile 1 -> buf 1 (12 loads in flight) --------
  gload_lds16(Ahg,       &Ah[0][wid << 9]);
  gload_lds16(Alg,       &Al[0][wid << 9]);
  gload_lds16(Bhg0,      &Bh[0][wid << 9]);
  gload_lds16(Bhg1,      &Bh[0][(wid + 8) << 9]);
  gload_lds16(Blg0,      &Bl[0][wid << 9]);
  gload_lds16(Blg1,      &Bl[0][(wid + 8) << 9]);
  gload_lds16(Ahg  + 32, &Ah[1][wid << 9]);
  gload_lds16(Alg  + 32, &Al[1][wid << 9]);
  gload_lds16(Bhg0 + 32, &Bh[1][wid << 9]);
  gload_lds16(Bhg1 + 32, &Bh[1][(wid + 8) << 9]);
  gload_lds16(Blg0 + 32, &Bl[1][wid << 9]);
  gload_lds16(Blg1 + 32, &Bl[1][(wid + 8) << 9]);

#pragma unroll 1
  for (int t = 0; t < 16; ++t) {
    const int cur = t % 3;
    const int pf  = (t + 2) % 3;
    const int pfo = (t + 2) * 32;
    const bool dopf = (t + 2) < 16;

    // gate: own tile-t loads complete; tile t+1 (6 loads) stays in flight
    if (t < 15) { asm volatile("s_waitcnt vmcnt(6)" ::: "memory"); }
    else        { asm volatile("s_waitcnt vmcnt(0)" ::: "memory"); }
    __builtin_amdgcn_s_barrier();

    // ---------------- phase 0: i{0,1} x j{0,1} ----------------
    const short8 a0h = *(const short8*)&Ah[cur][aoff];
    const short8 a1h = *(const short8*)&Ah[cur][aoff + 512];
    const short8 a0l = *(const short8*)&Al[cur][aoff];
    const short8 a1l = *(const short8*)&Al[cur][aoff + 512];
    const short8 b0h = *(const short8*)&Bh[cur][boff];
    const short8 b1h = *(const short8*)&Bh[cur][boff + 512];
    const short8 b0l = *(const short8*)&Bl[cur][boff];
    const short8 b1l = *(const short8*)&Bl[cur][boff + 512];
    if (dopf) {
      gload_lds16(Ahg + pfo, &Ah[pf][wid << 9]);
      gload_lds16(Alg + pfo, &Al[pf][wid << 9]);
    }
    __builtin_amdgcn_s_barrier();
    asm volatile("s_waitcnt lgkmcnt(0)" ::: "memory");
    __builtin_amdgcn_sched_barrier(0);
    __builtin_amdgcn_s_setprio(1);
    MFMA(acc[0][0], a0h, b0h); MFMA(acc[0][0], a0h, b0l); MFMA(acc[0][0], a0l, b0h);
    MFMA(acc[0][1], a0h, b1h); MFMA(acc[0][1], a0h, b1l); MFMA(acc[0][1], a0l, b1h);
    MFMA(acc[1][0], a1h, b0h); MFMA(acc[1][0], a1h, b0l); MFMA(acc[1][0], a1l, b0h);
    MFMA(acc[1][1], a1h, b1h); MFMA(acc[1][1], a1h, b1l); MFMA(acc[1][1], a1l, b1h);
    __builtin_amdgcn_s_setprio(0);
    __builtin_amdgcn_s_barrier();

    // ---------------- phase 1: i{0,1} x j{2,3} ----------------
    const short8 b2h = *(const short8*)&Bh[cur][boff + 1024];
    const short8 b3h = *(const short8*)&Bh[cur][boff + 1536];
    const short8 b2l = *(const short8*)&Bl[cur][boff + 1024];
    const short8 b3l = *(const short8*)&Bl[cur][boff + 1536];
    if (dopf) {
      gload_lds16(Bhg0 + pfo, &Bh[pf][wid << 9]);
      gload_lds16(Bhg1 + pfo, &Bh[pf][(wid + 8) << 9]);
    }
    __builtin_amdgcn_s_barrier();
    asm volatile("s_waitcnt lgkmcnt(0)" ::: "memory");
    __builtin_amdgcn_sched_barrier(0);
    __builtin_amdgcn_s_setprio(1);
    MFMA(acc[0][2], a0h, b2h); MFMA(acc[0][2], a0h, b2l); MFMA(acc[0][2], a0l, b2h);
    MFMA(acc[0][3], a0h, b3h); MFMA(acc[0][3], a0h, b3l); MFMA(acc[0][3], a0l, b3h);
    MFMA(acc[1][2], a1h, b2h); MFMA(acc[1][2], a1h, b2l); MFMA(acc[1][2], a1l, b2h);
    MFMA(acc[1][3], a1h, b3h); MFMA(acc[1][3], a1h, b3l); MFMA(acc[1][3], a1l, b3h);
    __builtin_amdgcn_s_setprio(0);
    __builtin_amdgcn_s_barrier();

    // ---------------- phase 2: i{2,3} x j{2,3} ----------------
    const short8 c0h = *(const short8*)&Ah[cur][aoff + 1024];
    const short8 c1h = *(const short8*)&Ah[cur][aoff + 1536];
    const short8 c0l = *(const short8*)&Al[cur][aoff + 1024];
    const short8 c1l = *(const short8*)&Al[cur][aoff + 1536];
    if (dopf) gload_lds16(Blg0 + pfo, &Bl[pf][wid << 9]);
    __builtin_amdgcn_s_barrier();
    asm volatile("s_waitcnt lgkmcnt(0)" ::: "memory");
    __builtin_amdgcn_sched_barrier(0);
    __builtin_amdgcn_s_setprio(1);
    MFMA(acc[2][2], c0h, b2h); MFMA(acc[2][2], c0h, b2l); MFMA(acc[2][2], c0l, b2h);
    MFMA(acc[2][3], c0h, b3h); MFMA(acc[2][3], c0h, b3l); MFMA(acc[2][3], c0l, b3h);
    MFMA(acc[3][2], c1h, b2h); MFMA(acc[3][2], c1h, b2l); MFMA(acc[3][2], c1l, b2h);
    MFMA(acc[3][3], c1h, b3h); MFMA(acc[3][3], c1h, b3l); MFMA(acc[3][3], c1l, b3h);
    __builtin_amdgcn_s_setprio(0);
    __builtin_amdgcn_s_barrier();

    // ---------------- phase 3: i{2,3} x j{0,1} (B01 reused from regs) ----------------
    if (dopf) gload_lds16(Blg1 + pfo, &Bl[pf][(wid + 8) << 9]);
    __builtin_amdgcn_s_barrier();
    __builtin_amdgcn_s_setprio(1);
    MFMA(acc[2][0], c0h, b0h); MFMA(acc[2][0], c0h, b0l); MFMA(acc[2][0], c0l, b0h);
    MFMA(acc[2][1], c0h, b1h); MFMA(acc[2][1], c0h, b1l); MFMA(acc[2][1], c0l, b1h);
    MFMA(acc[3][0], c1h, b0h); MFMA(acc[3][0], c1h, b0l); MFMA(acc[3][0], c1l, b0h);
    MFMA(acc[3][1], c1h, b1h); MFMA(acc[3][1], c1h, b1l); MFMA(acc[3][1], c1l, b1h);
    __builtin_amdgcn_s_setprio(0);
    __builtin_amdgcn_s_barrier();
  }

  // ---- fused argmin epilogue: score = e_norm[k] - 2*dot ----
  float en[4];
#pragma unroll
  for (int j = 0; j < 4; ++j)
    en[j] = e_norm[kbase + wcol * 64 + j * 16 + m16];

  __syncthreads();
  unsigned long long* red = (unsigned long long*)&Ah[0][0];   // [128][4], 4 KB
#pragma unroll
  for (int i = 0; i < 4; ++i) {
#pragma unroll
    for (int r = 0; r < 4; ++r) {
      unsigned long long best = 0xFFFFFFFFFFFFFFFFull;
#pragma unroll
      for (int j = 0; j < 4; ++j) {
        const float s = en[j] - 2.0f * acc[i][j][r];
        unsigned u = __float_as_uint(s);
        u = (u & 0x80000000u) ? ~u : (u | 0x80000000u);  // orderable bits
        const unsigned k = (unsigned)(kbase + wcol * 64 + j * 16 + m16);
        const unsigned long long c = ((unsigned long long)u << 32) | k;
        best = (c < best) ? c : best;
      }
#pragma unroll
      for (int s = 1; s < 16; s <<= 1) {
        const unsigned long long c = __shfl_xor(best, s);
        best = (c < best) ? c : best;
      }
      if (m16 == 0)
        red[(wrow * 64 + i * 16 + kq * 4 + r) * 4 + wcol] = best;
    }
  }
  __syncthreads();
  if (tid < 128) {
    unsigned long long m = red[tid * 4];
#pragma unroll
    for (int c = 1; c < 4; ++c) {
      const unsigned long long v = red[tid * 4 + c];
      m = (v < m) ? v : m;
    }
    atomicMin(&partials[tokbase + tid], m);
  }
}

// ============ K4: gather quantize + EMA scatter stats + loss ============
__global__ __launch_bounds__(128) void gather_stats_kernel(
    const float* __restrict__ x, const float* __restrict__ embedT,
    const unsigned long long* __restrict__ partials,
    float* __restrict__ quant_out, float* __restrict__ indf_out,
    float* __restrict__ embed_sumT, float* __restrict__ onehot,
    float* __restrict__ scal) {
  const int n = blockIdx.x;
  __shared__ int s_ind;
  __shared__ float wsum[2];
  if (threadIdx.x == 0) {
    const int k = (int)(partials[n] & 0xFFFFFFFFull);
    s_ind = k;
    indf_out[n] = (float)k;
    atomicAdd(&onehot[k], 1.0f);
  }
  __syncthreads();
  const int k = s_ind;
  const int d4 = threadIdx.x * 4;    // 128 threads * 4 = 512 = DDIM
  const float4 e  = *(const float4*)&embedT[(size_t)k * DDIM + d4];
  const float4 xv = *(const float4*)&x[(size_t)n * DDIM + d4];
  *(float4*)&quant_out[(size_t)n * DDIM + d4] = e;
  atomicAdd(&embed_sumT[(size_t)k * DDIM + d4 + 0], xv.x);
  atomicAdd(&embed_sumT[(size_t)k * DDIM + d4 + 1], xv.y);
  atomicAdd(&embed_sumT[(size_t)k * DDIM + d4 + 2], xv.z);
  atomicAdd(&embed_sumT[(size_t)k * DDIM + d4 + 3], xv.w);
  const float dx0 = e.x - xv.x, dx1 = e.y - xv.y, dx2 = e.z - xv.z, dx3 = e.w - xv.w;
  float ls = dx0 * dx0 + dx1 * dx1 + dx2 * dx2 + dx3 * dx3;
#pragma unroll
  for (int off = 32; off > 0; off >>= 1) ls += __shfl_down(ls, off);
  if ((threadIdx.x & 63) == 0) wsum[threadIdx.x >> 6] = ls;
  __syncthreads();
  if (threadIdx.x == 0) atomicAdd(&scal[0], wsum[0] + wsum[1]);
}

// ============ K5: cluster-size EMA + total-count reduction ============
__global__ __launch_bounds__(256) void cluster_kernel(
    const float* __restrict__ cluster_size, const float* __restrict__ onehot,
    float* __restrict__ ncs_out, float* __restrict__ scal) {
  const int k = blockIdx.x * 256 + threadIdx.x;
  const float v = cluster_size[k] * DECAYF + (1.0f - DECAYF) * onehot[k];
  ncs_out[k] = v;
  float s = v;
#pragma unroll
  for (int off = 32; off > 0; off >>= 1) s += __shfl_down(s, off);
  __shared__ float w[4];
  if ((threadIdx.x & 63) == 0) w[threadIdx.x >> 6] = s;
  __syncthreads();
  if (threadIdx.x == 0) atomicAdd(&scal[1], w[0] + w[1] + w[2] + w[3]);
}

// ============ K6: new_embed_avg + new_embed + loss (odd offset -> scalar) ============
__global__ __launch_bounds__(256) void finalize_kernel(
    const float* __restrict__ embed_avg, const float* __restrict__ embed_sumT,
    const float* __restrict__ ncs, const float* __restrict__ scal,
    float* __restrict__ out_embed, float* __restrict__ out_avg,
    float* __restrict__ out_loss) {
  const int idx = blockIdx.x * 256 + threadIdx.x;   // [D][K] layout
  const int d = idx >> 13;
  const int k = idx & (KCODES - 1);
  const float ea = embed_avg[idx];
  const float es = embed_sumT[(size_t)k * DDIM + d];
  const float nea = DECAYF * ea + (1.0f - DECAYF) * es;
  out_avg[idx] = nea;
  const float nsum = scal[1];
  const float cs = (ncs[k] + EPSF) / (nsum + (float)KCODES * EPSF) * nsum;
  out_embed[idx] = nea / cs;
  if (idx == 0) out_loss[0] = scal[0] * (1.0f / ((float)NTOK * (float)DDIM));
}

extern "C" void kernel_launch(void* const* d_in, const int* in_sizes, int n_in,
                              void* d_out, int out_size, void* d_ws, size_t ws_size,
                              hipStream_t stream) {
  (void)in_sizes; (void)n_in; (void)out_size; (void)ws_size;
  const float* x            = (const float*)d_in[0];   // [NTOK, 512]
  const float* embed        = (const float*)d_in[1];   // [D, K]
  const float* cluster_size = (const float*)d_in[2];   // [K]
  const float* embed_avg    = (const float*)d_in[3];   // [D, K]

  float* out = (float*)d_out;
  float* out_quant = out;                               // 16777216
  float* out_indf  = out + 16777216;                    // 32768
  float* out_loss  = out + 16777216 + 32768;            // 1
  float* out_embed = out + 16777216 + 32768 + 1;        // 4194304 (odd offset)
  float* out_ncs   = out_embed + DK;                    // 8192
  float* out_avg   = out_ncs + KCODES;                  // 4194304

  float* ws = (float*)d_ws;
  float* esumT  = ws + WS_ESUMT;
  float* onehot = ws + WS_ONEHOT;
  float* e_norm = ws + WS_ENORM;
  float* scal   = ws + WS_SCAL;
  unsigned long long* partials = (unsigned long long*)(ws + WS_PART);
  float* embedT = ws + WS_EMBEDT;
  unsigned short* ehi = (unsigned short*)(ws + WS_EHI);
  unsigned short* elo = (unsigned short*)(ws + WS_ELO);

  // x hi/lo scratch lives in the out_quant region; overwritten by gather later.
  unsigned short* xhi = (unsigned short*)d_out;
  unsigned short* xlo = xhi + (size_t)NTOK * DDIM;

  hipMemsetAsync(d_ws, 0, WS_ZERO_BYTES, stream);
  hipMemsetAsync((char*)d_ws + (size_t)WS_PART * 4, 0xFF, (size_t)NTOK * 8, stream);

  split_x_kernel<<<NTOK * DDIM / 8 / 256, 256, 0, stream>>>(x, xhi, xlo);
  transpose_split_kernel<<<dim3(KCODES / 32, DDIM / 32), dim3(32, 8), 0, stream>>>(
      embed, embedT, ehi, elo, e_norm);

  argmin_mfma_kernel<<<dim3(KCODES / 256, NTOK / 128), 512, 0, stream>>>(
      xhi, xlo, ehi, elo, e_norm, partials);

  gather_stats_kernel<<<NTOK, 128, 0, stream>>>(
      x, embedT, partials, out_quant, out_indf, esumT, onehot, scal);

  cluster_kernel<<<KCODES / 256, 256, 0, stream>>>(cluster_size, onehot, out_ncs, scal);

  finalize_kernel<<<DK / 256, 256, 0, stream>>>(
      embed_avg, esumT, out_ncs, scal, out_embed, out_avg, out_loss);
}